// Round 6
// baseline (718.764 us; speedup 1.0000x reference)
//
#include <hip/hip_runtime.h>
#include <math.h>

#define WE 300
#define DEp 256
#define VV 50000
#define DDim 100000
#define BB 4096
#define NGc 10
#define NENT 45056           // 4096 * 11
#define TRV_TILE 64
#define TRV_BLOCKS 782       // ceil(50000/64)
#define RDL_TILE 48
#define RDL_BLOCKS 2084      // ceil(100000/48)

__device__ __forceinline__ float wave_reduce(float v) {
    #pragma unroll
    for (int o = 32; o > 0; o >>= 1) v += __shfl_down(v, o, 64);
    return v;
}

// log(sigmoid(x)), numerically stable
__device__ __forceinline__ float logsigf(float x) {
    return (x >= 0.f) ? -log1pf(expf(-x)) : x - log1pf(expf(x));
}

// Kernel 1: transpose rv (300 x 50000) -> rvT (50000 x 300).
// Tile = 64 cols x all 300 rows. Reads: float4, 256B segments per row.
// Writes: ONE dense contiguous 64*1200B = 76.8KB region per block.
// Block 0 additionally zero-inits the 515 doubles (rowsum/rowsq/accs).
__global__ __launch_bounds__(256) void k_T_rv(const float* __restrict__ rv,
                                              float* __restrict__ rvT,
                                              double* __restrict__ zbase) {
    if (blockIdx.x == 0) {
        for (int i = threadIdx.x; i < 515; i += 256) zbase[i] = 0.0;
    }
    __shared__ float sd[TRV_TILE][301];
    int n0 = blockIdx.x * TRV_TILE;
    int t = threadIdx.x;
    // load: 300 rows x 16 float4 = 4800 float4
    for (int idx = t; idx < 300 * 16; idx += 256) {
        int f = idx & 15;          // float4 index within the 64-col tile
        int w = idx >> 4;          // row 0..299
        int n = n0 + f * 4;
        float4 v = make_float4(0.f, 0.f, 0.f, 0.f);
        if (n + 3 < VV) v = *(const float4*)(rv + (size_t)w * VV + n);
        sd[f * 4 + 0][w] = v.x;
        sd[f * 4 + 1][w] = v.y;
        sd[f * 4 + 2][w] = v.z;
        sd[f * 4 + 3][w] = v.w;
    }
    __syncthreads();
    // store: 64 rows x 75 float4 = 4800 float4, fully dense contiguous region
    for (int idx = t; idx < TRV_TILE * 75; idx += 256) {
        int f4 = idx % 75, row = idx / 75;
        int n = n0 + row;
        if (n < VV) {
            float4 v = make_float4(sd[row][f4 * 4 + 0], sd[row][f4 * 4 + 1],
                                   sd[row][f4 * 4 + 2], sd[row][f4 * 4 + 3]);
            *(float4*)(rvT + (size_t)n * WE + f4 * 4) = v;
        }
    }
}

// Kernel 2: fused gather + normalize + GEMM + row-stats partials + sum(proj^2).
// 256 blocks, 16 b each. Tile: 16 b x 64 de per de0 pass; thread = (tx: 4 de, ty: 1 b).
__global__ __launch_bounds__(256) void k_ggs(const float* __restrict__ rvT,
                                             const float* __restrict__ proj,
                                             const int* __restrict__ wid,
                                             float* __restrict__ tpre,
                                             double* __restrict__ rowsum,
                                             double* __restrict__ rowsq,
                                             double* __restrict__ proj_acc) {
    __shared__ float sN[16][321];      // normed [b][k], stride 321 (321%32=1: spread banks)
    __shared__ float As[64][33];       // proj subtile [de][k]
    __shared__ float sS[256], sSS[256];
    __shared__ float partn[16][4];
    __shared__ float sInv[16];
    __shared__ int ids[160];
    __shared__ float ppart[4];
    int t = threadIdx.x;
    int b0 = blockIdx.x * 16;
    if (t < 160) ids[t] = wid[b0 * NGc + t];
    sS[t] = 0.f; sSS[t] = 0.f;
    if (t < 16) {
        #pragma unroll
        for (int q = 300; q < 321; ++q) sN[t][q] = 0.f;
    }
    __syncthreads();

    // gather: thread t owns w = t (and w2 = 256+t for t < 44)
    float g1[16], g2[16];
    #pragma unroll
    for (int b = 0; b < 16; ++b) { g1[b] = 0.f; g2[b] = 0.f; }
    bool has2 = (t < WE - 256);
    #pragma unroll
    for (int b = 0; b < 16; ++b) {
        #pragma unroll
        for (int ng = 0; ng < NGc; ++ng) {
            const float* rowp = rvT + (size_t)ids[b * 10 + ng] * WE;
            g1[b] += rowp[t];
            if (has2) g2[b] += rowp[256 + t];
        }
    }
    int lane = t & 63, wv = t >> 6;
    #pragma unroll
    for (int b = 0; b < 16; ++b) {
        float p = g1[b] * g1[b] + (has2 ? g2[b] * g2[b] : 0.f);
        float r = wave_reduce(p);
        if (lane == 0) partn[b][wv] = r;
    }
    __syncthreads();
    if (t < 16)
        sInv[t] = 1.0f / sqrtf(partn[t][0] + partn[t][1] + partn[t][2] + partn[t][3]);
    __syncthreads();
    #pragma unroll
    for (int b = 0; b < 16; ++b) {
        sN[b][t] = g1[b] * sInv[b];
        if (has2) sN[b][256 + t] = g2[b] * sInv[b];
    }
    // (kt-loop top __syncthreads protects sN reads)

    // GEMM: per de0 pass, 64 de x 16 b; thread owns de = de0+tx*4+i (i<4), b = b0+ty.
    int tx = t & 15, ty = t >> 4;
    float ps = 0.f;
    for (int de0 = 0; de0 < DEp; de0 += 64) {
        float acc[4] = {};
        for (int kt = 0; kt < 10; ++kt) {
            int k0 = kt * 32;
            __syncthreads();
            for (int idx = t; idx < 2048; idx += 256) {
                int r = idx >> 5, kk = idx & 31;
                int k = k0 + kk;
                float v = 0.f;
                if (k < WE) v = proj[(size_t)(de0 + r) * WE + k];
                As[r][kk] = v;
                ps += v * v;
            }
            __syncthreads();
            #pragma unroll
            for (int kk = 0; kk < 32; ++kk) {
                float bv = sN[ty][k0 + kk];
                #pragma unroll
                for (int i = 0; i < 4; ++i) acc[i] += As[tx * 4 + i][kk] * bv;
            }
        }
        int b = b0 + ty;
        float4 v = make_float4(acc[0], acc[1], acc[2], acc[3]);
        *(float4*)(tpre + (size_t)b * DEp + de0 + tx * 4) = v;
        #pragma unroll
        for (int i = 0; i < 4; ++i) {
            atomicAdd(&sS[de0 + tx * 4 + i], acc[i]);
            atomicAdd(&sSS[de0 + tx * 4 + i], acc[i] * acc[i]);
        }
    }
    __syncthreads();
    atomicAdd(&rowsum[t], (double)sS[t]);
    atomicAdd(&rowsq[t], (double)sSS[t]);
    if (blockIdx.x == 0) {   // this block staged ALL of proj across its tiles
        float r = wave_reduce(ps);
        if (lane == 0) ppart[wv] = r;
        __syncthreads();
        if (t == 0)
            atomicAdd(proj_acc, (double)(ppart[0] + ppart[1] + ppart[2] + ppart[3]));
    }
}

// Kernel 3: fused rd-stream + loss + sum(rd^2) + stats finalize.
// Block = 48-col panel x full 256 de staged in LDS. Each wave ballot-scans
// its quarter of the 45056 entries; matched entries get the FULL dot here
// (one wave_reduce per entry), logsig term accumulated per-wave.
__global__ __launch_bounds__(256) void k_rdloss(const float* __restrict__ rd,
                                                const float* __restrict__ tpre,
                                                const float* __restrict__ beta,
                                                const int* __restrict__ doc,
                                                const int* __restrict__ neg,
                                                const double* __restrict__ rowsum,
                                                const double* __restrict__ rowsq,
                                                double* __restrict__ accs) { // [0]=data [1]=rd
    __shared__ float sd[RDL_TILE][257];
    __shared__ float sM[256], sSc[256], sB[256];
    __shared__ float rpart[4];
    int t = threadIdx.x;
    int p = blockIdx.x;
    int c0 = p * RDL_TILE;
    {   // stats finalize (redundant per block, trivial)
        double s = rowsum[t], ss = rowsq[t];
        double mean = s / (double)BB;
        double var = (ss - s * s / (double)BB) / (double)(BB - 1);
        sM[t]  = (float)mean;
        sSc[t] = (float)(1.0 / sqrt(sqrt(var)));   // reference: /sqrt(std) = var^-1/4
        sB[t]  = beta[t];
    }
    float ssq = 0.f;
    for (int idx = t; idx < RDL_TILE * DEp; idx += 256) {   // 12288/256 = 48
        int c = idx % RDL_TILE, de = idx / RDL_TILE;
        int col = c0 + c;
        float v = 0.f;
        if (col < DDim) v = rd[(size_t)de * DDim + col];
        sd[c][de] = v;
        ssq += v * v;
    }
    int lane = t & 63, wv = t >> 6;
    float r = wave_reduce(ssq);
    if (lane == 0) rpart[wv] = r;
    __syncthreads();
    if (t == 0)
        atomicAdd(&accs[1], (double)(rpart[0] + rpart[1] + rpart[2] + rpart[3]));

    float wsum = 0.f;
    for (int i = 0; i < 176; ++i) {            // 4 waves * 11264 = 45056 entries
        int e = wv * 11264 + i * 64 + lane;
        int b = e / 11;
        int j = e - b * 11;
        int id = (j == 0) ? doc[b] : neg[b * NGc + j - 1];
        int pp = id / RDL_TILE;
        unsigned long long mask = __ballot(pp == p);
        while (mask) {
            int src = __ffsll(mask) - 1;
            mask &= mask - 1;
            int bb = __shfl(b, src, 64);
            int jj = __shfl(j, src, 64);
            int cc = __shfl(id - pp * RDL_TILE, src, 64);
            float acc = 0.f;
            #pragma unroll
            for (int q = 0; q < 4; ++q) {
                int de = q * 64 + lane;
                float tv = (tpre[(size_t)bb * DEp + de] - sM[de]) * sSc[de] + sB[de];
                tv = fminf(1.f, fmaxf(-1.f, tv));
                acc += tv * sd[cc][de];
            }
            float x = wave_reduce(acc);
            if (lane == 0) {
                float term;
                if (jj == 0) term = 10.f * fminf(logsigf(x), -1.0005003e-3f);
                else         term = fmaxf(logsigf(-x), -4.6051702f);
                wsum += term;
            }
        }
    }
    if (lane == 0) atomicAdd(&accs[0], (double)wsum);
}

__global__ void k_final(const double* __restrict__ accs, float* __restrict__ out) {
    // accs: [0]=data sum (raw terms), [1]=sum rd^2, [2]=sum proj^2
    out[0] = (float)(0.55 * accs[0] / (double)BB
                     + (0.01 / (2.0 * (double)BB)) * (accs[1] + accs[2]));
}

extern "C" void kernel_launch(void* const* d_in, const int* in_sizes, int n_in,
                              void* d_out, int out_size, void* d_ws, size_t ws_size,
                              hipStream_t stream) {
    const float* rv   = (const float*)d_in[0];
    const float* rd   = (const float*)d_in[1];
    const float* proj = (const float*)d_in[2];
    const float* beta = (const float*)d_in[3];
    const int* wid    = (const int*)d_in[4];
    const int* doc    = (const int*)d_in[5];
    const int* neg    = (const int*)d_in[6];
    float* out = (float*)d_out;
    char* ws = (char*)d_ws;

    // workspace: rvT 60,000,000 | tpre 4,194,304 | 515 doubles
    float*  rvT    = (float*)(ws);
    float*  tpre   = (float*)(ws + 60000000);
    double* zbase  = (double*)(ws + 64194304);     // rowsum[256], rowsq[256], accs[3]
    double* rowsum = zbase;
    double* rowsq  = zbase + 256;
    double* accs   = zbase + 512;

    k_T_rv  <<<TRV_BLOCKS, 256, 0, stream>>>(rv, rvT, zbase);
    k_ggs   <<<256, 256, 0, stream>>>(rvT, proj, wid, tpre, rowsum, rowsq, accs + 2);
    k_rdloss<<<RDL_BLOCKS, 256, 0, stream>>>(rd, tpre, beta, doc, neg, rowsum, rowsq, accs);
    k_final <<<1, 1, 0, stream>>>(accs, out);
}